// Round 7
// baseline (151.480 us; speedup 1.0000x reference)
//
#include <hip/hip_runtime.h>
#include <hip/hip_bf16.h>

// MoCo loss on MI355X. V=2, N=1024, D=128, K=65536, fp32 in, 2 fp32 scalars out.
// R15: 3-launch pipeline:
//   prep_k  (1568): conv [0,1024) | intra [1024,1536) | loss1 [1536,1568)
//                   blocks 0-7 also zero QS for megaq atomics.
//   megaq_k (2048): pure queue GEMM, R13 no-barrier shape, TWO tiles per
//                   step + pair prefetch (8 x 16B loads in flight vs 4) to
//                   cover ~600cyc L2-miss latency. Atomic finish into QS.
//   final2_k (1):   IPart reduce + loss2 assembly + loss1 fold.
// R14 lesson: LDS-sharing + barrier/iter = 60us (vmcnt(0) drain per iter).
// R13 lesson: occupancy 2x at same shape = no change -> latency/MLP bound.
// R12 lesson: compile-time trip count -> full unroll -> 180 VGPR. Keep
//             runtime wt/wtEnd bounds.
//
// loss2 row sums: den += exp(-c), num += c*exp(-c), c = 2-2*dot.
// QS atomics: ws[row] += Se, ws[1024+row] += 2*(Se-Sde).
//
// ws floats:
//   [0,2048)        QS_e[1024], QS_ce[1024]     (atomic accum)
//   [2048,6144)     IS (fallback only)
//   [6144,8192)     l1part[2048]
//   [139264,172032) IPart[16][2][1024]   slot = x*8+yg
//   byte 2 MB+:     Bblk (bf16, 16 MB)
//
// MFMA 16x16x32 bf16: A[m=lane&15][k=quad*8+j]; B[k=quad*8+j][n=lane&15];
// C: col=lane&15, row=quad*4+reg.

#define NROWS 1024
#define DDIM  128
#define KQ    65536
#define NTILE 4096          // 65536/16 col-tiles
#define SLICE 512           // tiles per XCD slice (512*4KB = 2MB)
#define SUB   8
#define QPART 8192
#define IPART 139264
#define BBLK_BYTE_OFF (2u*1024u*1024u)
#define TWO_LOG2E 2.8853900817779268f

#define PREP_CONV  1024
#define PREP_INTRA 1536
#define PREP_TOTAL 1568

typedef __attribute__((ext_vector_type(8))) short  short8;
typedef __attribute__((ext_vector_type(4))) float  float4v;

#if __has_builtin(__builtin_amdgcn_exp2f)
#define EXP2(x) __builtin_amdgcn_exp2f(x)
#else
#define EXP2(x) __expf((x) * 0.6931471805599453f)
#endif

__device__ __forceinline__ unsigned short f2bf(float f) {
  unsigned u = __float_as_uint(f);
  u += 0x7FFF + ((u >> 16) & 1);           // RNE
  return (unsigned short)(u >> 16);
}

__device__ __forceinline__ short8 cvt8(const float* __restrict__ p) {
  float4 a = *(const float4*)p;
  float4 b = *(const float4*)(p + 4);
  short8 r;
  r[0] = (short)f2bf(a.x); r[1] = (short)f2bf(a.y);
  r[2] = (short)f2bf(a.z); r[3] = (short)f2bf(a.w);
  r[4] = (short)f2bf(b.x); r[5] = (short)f2bf(b.y);
  r[6] = (short)f2bf(b.z); r[7] = (short)f2bf(b.w);
  return r;
}

__device__ __forceinline__ float wave_sum(float v) {
  #pragma unroll
  for (int o = 32; o > 0; o >>= 1) v += __shfl_down(v, o, 64);
  return v;
}

__global__ void zero_ws(float* __restrict__ ws) {
  ws[blockIdx.x * 256 + threadIdx.x] = 0.f;   // fallback only
}

// ---------- prep: conv | intra | loss1 in one launch ----------

__global__ __launch_bounds__(256) void prep_k(
    const float* __restrict__ queue, const float* __restrict__ q,
    const float* __restrict__ kin, unsigned short* __restrict__ Bblk,
    float* __restrict__ ws) {
  __shared__ float lf[128][65];              // conv staging (33KB)
  __shared__ float l_e[4][32], l_de[4][32];  // intra reduce
  const int b    = (int)blockIdx.x;
  const int tid  = (int)threadIdx.x;
  const int lane = tid & 63;
  const int wave = tid >> 6;
  const int quad = lane >> 4;
  const int m    = lane & 15;

  if (b < PREP_CONV) {
    // ---- conv: 64 cols x 128 d via LDS transpose (R14 conv, verified)
    if (b < 8) ws[b * 256 + tid] = 0.f;      // zero QS region
    const int xcd   = b & 7;
    const int idx   = b >> 3;                // 0..127
    const int c0    = xcd * (SLICE * 16) + idx * 64;
    const int tile0 = xcd * SLICE + idx * 4;

    const int rl = tid >> 4;                 // 0..15
    const int cl = (tid & 15) * 4;           // 0..60
    #pragma unroll
    for (int p = 0; p < 8; ++p) {
      const int d = p * 16 + rl;
      float4 v = *(const float4*)(queue + (size_t)d * KQ + c0 + cl);
      lf[d][cl + 0] = v.x; lf[d][cl + 1] = v.y;
      lf[d][cl + 2] = v.z; lf[d][cl + 3] = v.w;
    }
    __syncthreads();
    #pragma unroll
    for (int s = 0; s < 4; ++s) {
      const int kk2  = tid >> 6;             // 0..3
      const int e8   = tid & 63;             // quad*16+n
      const int q2   = e8 >> 4, n = e8 & 15;
      const int dbase = kk2 * 32 + q2 * 8;
      const int col   = s * 16 + n;
      short8 sv;
      #pragma unroll
      for (int j = 0; j < 8; ++j) sv[j] = (short)f2bf(lf[dbase + j][col]);
      *(short8*)(Bblk + ((size_t)(tile0 + s) * 4 + kk2) * 512 + e8 * 8) = sv;
    }
  } else if (b < PREP_INTRA) {
    // ---- intra 2-rg (verified): b' = rowblk | yg<<5 | x<<8
    const int bp = b - PREP_CONV;
    const int rowblk = bp & 31;
    const int yg = (bp >> 5) & 7;
    const int x  = bp >> 8;
    const float* qx = q + (size_t)x * NROWS * DDIM;
    const int rowBase = rowblk * 32;

    short8 a[2][4];
    #pragma unroll
    for (int rg = 0; rg < 2; ++rg)
      #pragma unroll
      for (int kk = 0; kk < 4; ++kk)
        a[rg][kk] = cvt8(qx + (size_t)(rowBase + rg * 16 + m) * DDIM + kk * 32 + quad * 8);

    float ae[2][4] = {}, ade[2][4] = {};
    for (int jt = yg * 4 + wave; jt < NROWS / 16; jt += 32) {
      short8 bfr[4];
      #pragma unroll
      for (int kk = 0; kk < 4; ++kk)
        bfr[kk] = cvt8(qx + (size_t)(jt * 16 + m) * DDIM + kk * 32 + quad * 8);
      const int dgRg = (jt * 16 - rowBase) >> 4;
      #pragma unroll
      for (int rg = 0; rg < 2; ++rg) {
        float4v C = {0.f, 0.f, 0.f, 0.f};
        #pragma unroll
        for (int kk = 0; kk < 4; ++kk)
          C = __builtin_amdgcn_mfma_f32_16x16x32_bf16(a[rg][kk], bfr[kk], C, 0, 0, 0);
        #pragma unroll
        for (int r = 0; r < 4; ++r) {
          float d = C[r];
          float e = EXP2(fmaf(d, TWO_LOG2E, -TWO_LOG2E));
          float de = d * e;
          if (rg == dgRg && (quad * 4 + r) == m) { e = 0.f; de = 0.f; }
          ae[rg][r] += e;
          ade[rg][r] += de;
        }
      }
    }
    #pragma unroll
    for (int rg = 0; rg < 2; ++rg)
      #pragma unroll
      for (int r = 0; r < 4; ++r) {
        float e = ae[rg][r], de = ade[rg][r];
        #pragma unroll
        for (int mk = 8; mk >= 1; mk >>= 1) {
          e  += __shfl_xor(e,  mk, 64);
          de += __shfl_xor(de, mk, 64);
        }
        if (m == 0) {
          l_e[wave][rg * 16 + quad * 4 + r]  = e;
          l_de[wave][rg * 16 + quad * 4 + r] = de;
        }
      }
    __syncthreads();
    if (tid < 32) {
      float E = l_e[0][tid] + l_e[1][tid] + l_e[2][tid] + l_e[3][tid];
      float D = l_de[0][tid] + l_de[1][tid] + l_de[2][tid] + l_de[3][tid];
      const int slot = x * 8 + yg;
      ws[IPART + (size_t)slot * 2048 + rowBase + tid]        = E;
      ws[IPART + (size_t)slot * 2048 + 1024 + rowBase + tid] = D;
    }
  } else {
    // ---- loss1 (verified): wave handles 16 (x,i) rows
    const int gw0 = (b - PREP_INTRA) * 4 + wave;   // 0..127
    for (int t = 0; t < 16; ++t) {
      const int idx = gw0 * 16 + t;                // 0..2047
      const int x = idx >> 10;
      const int i = idx & 1023;
      const float2* qp = (const float2*)(q + (size_t)(x * NROWS + i) * DDIM);
      const float2* kp = (const float2*)(kin + (size_t)((1 - x) * NROWS + i) * DDIM);
      float2 av = qp[lane];
      float2 bv = kp[lane];
      float s = wave_sum(av.x * bv.x + av.y * bv.y);
      if (lane == 0) ws[6144 + idx] = s;
    }
  }
}

// ---------- megaq: pure queue GEMM, 2 tiles/step + pair prefetch ----------

__global__ __launch_bounds__(256) void megaq_k(
    const float* __restrict__ q, const unsigned short* __restrict__ Bblk,
    float* __restrict__ ws) {
  const int fb   = (int)blockIdx.x;          // 2048 blocks, %8==0 swizzle
  const int xcd  = fb & 7;
  const int t    = fb >> 3;                  // 0..255
  const int rowBase = (t & 31) * 32;
  const int sub  = t >> 5;                   // 0..7
  const int tid  = (int)threadIdx.x;
  const int lane = tid & 63;
  const int wave = tid >> 6;
  const int quad = lane >> 4;
  const int m    = lane & 15;

  short8 a[2][4];
  #pragma unroll
  for (int rg = 0; rg < 2; ++rg)
    #pragma unroll
    for (int kk = 0; kk < 4; ++kk)
      a[rg][kk] = cvt8(q + (size_t)(rowBase + rg * 16 + m) * DDIM + kk * 32 + quad * 8);

  float ae[2][4] = {}, ade[2][4] = {};

  const int ST = SUB * 4;                    // 32
  int wt = xcd * SLICE + sub * 4 + wave;     // 16 tiles/wave, pairs of 2
  const int wtEnd = (xcd + 1) * SLICE;

  short8 c0[4], c1[4];
  {
    const unsigned short* bp = Bblk + (size_t)wt * 2048 + lane * 8;
    #pragma unroll
    for (int kk = 0; kk < 4; ++kk) c0[kk] = *(const short8*)(bp + kk * 512);
    const unsigned short* bq = bp + (size_t)ST * 2048;
    #pragma unroll
    for (int kk = 0; kk < 4; ++kk) c1[kk] = *(const short8*)(bq + kk * 512);
  }
  while (true) {
    const int wn = wt + 2 * ST;
    const bool more = wn < wtEnd;
    short8 n0[4], n1[4];
    if (more) {
      const unsigned short* bp = Bblk + (size_t)wn * 2048 + lane * 8;
      #pragma unroll
      for (int kk = 0; kk < 4; ++kk) n0[kk] = *(const short8*)(bp + kk * 512);
      const unsigned short* bq = bp + (size_t)ST * 2048;
      #pragma unroll
      for (int kk = 0; kk < 4; ++kk) n1[kk] = *(const short8*)(bq + kk * 512);
    }
    #pragma unroll
    for (int rg = 0; rg < 2; ++rg) {
      float4v C = {0.f, 0.f, 0.f, 0.f};
      #pragma unroll
      for (int kk = 0; kk < 4; ++kk)
        C = __builtin_amdgcn_mfma_f32_16x16x32_bf16(a[rg][kk], c0[kk], C, 0, 0, 0);
      float4v C2 = {0.f, 0.f, 0.f, 0.f};
      #pragma unroll
      for (int kk = 0; kk < 4; ++kk)
        C2 = __builtin_amdgcn_mfma_f32_16x16x32_bf16(a[rg][kk], c1[kk], C2, 0, 0, 0);
      #pragma unroll
      for (int r = 0; r < 4; ++r) {
        float d = C[r];
        float e = EXP2(fmaf(d, TWO_LOG2E, -TWO_LOG2E));
        ae[rg][r] += e;
        ade[rg][r] = fmaf(d, e, ade[rg][r]);
        float d2 = C2[r];
        float e2 = EXP2(fmaf(d2, TWO_LOG2E, -TWO_LOG2E));
        ae[rg][r] += e2;
        ade[rg][r] = fmaf(d2, e2, ade[rg][r]);
      }
    }
    if (!more) break;
    wt = wn;
    #pragma unroll
    for (int kk = 0; kk < 4; ++kk) { c0[kk] = n0[kk]; c1[kk] = n1[kk]; }
  }

  // wave-private rows: reduce over m (cols) then atomic into QS
  #pragma unroll
  for (int rg = 0; rg < 2; ++rg)
    #pragma unroll
    for (int r = 0; r < 4; ++r) {
      float e = ae[rg][r], de = ade[rg][r];
      #pragma unroll
      for (int mk = 8; mk >= 1; mk >>= 1) {
        e  += __shfl_xor(e,  mk, 64);
        de += __shfl_xor(de, mk, 64);
      }
      if (m == 0) {
        const int row = rowBase + rg * 16 + quad * 4 + r;
        atomicAdd(&ws[row],        e);
        atomicAdd(&ws[1024 + row], 2.f * (e - de));
      }
    }
}

// ---------- final2: IPart reduce + loss2 + loss1 fold, single block ----------

__global__ void final2_k(const float* __restrict__ ws, float* __restrict__ out) {
  const float* l1part = ws + 6144;
  __shared__ float red1[256], red2[256];
  float p1 = 0.f, p2 = 0.f;
  for (int idx = (int)threadIdx.x; idx < 2048; idx += 256) {
    int x = idx >> 10;
    int i = idx & 1023;
    p1 += 2.f - 2.f * l1part[idx];
    float E = 0.f, D = 0.f;
    #pragma unroll
    for (int g = 0; g < 8; ++g) {
      const int s = x * 8 + g;
      E += ws[IPART + (size_t)s * 2048 + i];
      D += ws[IPART + (size_t)s * 2048 + 1024 + i];
    }
    float den = ws[i]        + E;
    float num = ws[1024 + i] + 2.f * (E - D);
    p2 += num / den;
  }
  red1[threadIdx.x] = p1;
  red2[threadIdx.x] = p2;
  __syncthreads();
  for (int s = 128; s > 0; s >>= 1) {
    if ((int)threadIdx.x < s) {
      red1[threadIdx.x] += red1[threadIdx.x + s];
      red2[threadIdx.x] += red2[threadIdx.x + s];
    }
    __syncthreads();
  }
  if (threadIdx.x == 0) {
    out[0] = red1[0] * (1.f / (2.f * NROWS));
    out[1] = -red2[0] * (1.f / (2.f * NROWS));
  }
}

// ---------- chunked fallback (ws too small for full Bblk) ----------

__global__ void conv_B_ck(const float* __restrict__ queue,
                          unsigned short* __restrict__ Bblk, int c0chunk) {
  const int tid  = (int)threadIdx.x;
  const int g    = tid >> 4;
  const int ci   = (tid & 15) * 4;
  const int cloc = (int)blockIdx.x * 64 + ci;
  const int c    = c0chunk + cloc;
  const int d0   = g * 8;
  const int kk   = g >> 2;
  const int quad = g & 3;
  float4v v[8];
  #pragma unroll
  for (int dd = 0; dd < 8; ++dd)
    v[dd] = *(const float4v*)(queue + (size_t)(d0 + dd) * KQ + c);
  unsigned short* outp = Bblk + ((size_t)(cloc >> 4) * 4 + kk) * 512
                              + (quad * 16 + (cloc & 15)) * 8;
  #pragma unroll
  for (int n = 0; n < 4; ++n) {
    short8 s;
    #pragma unroll
    for (int dd = 0; dd < 8; ++dd)
      s[dd] = (short)f2bf(v[dd][n]);
    *(short8*)(outp + n * 8) = s;
  }
}

__global__ __launch_bounds__(256) void mfma_queue_ck(
    const float* __restrict__ q, const unsigned short* __restrict__ Bblk,
    int cnt, float* __restrict__ acc_e, float* __restrict__ acc_ce) {
  const int lane = (int)threadIdx.x & 63;
  const int wave = (int)threadIdx.x >> 6;
  const int quad = lane >> 4;
  const int m    = lane & 15;
  const int rowBase = (int)blockIdx.x * 64;

  short8 a[4][4];
  #pragma unroll
  for (int rg = 0; rg < 4; ++rg)
    #pragma unroll
    for (int kk = 0; kk < 4; ++kk)
      a[rg][kk] = cvt8(q + (size_t)(rowBase + rg * 16 + m) * DDIM + kk * 32 + quad * 8);

  float ae[4][4] = {}, ade[4][4] = {};
  const int stride = (int)gridDim.y * 4;
  int wt = (int)blockIdx.y * 4 + wave;
  if (wt < cnt) {
    short8 bc[4];
    {
      const unsigned short* bp = Bblk + (size_t)wt * 2048 + lane * 8;
      #pragma unroll
      for (int kk = 0; kk < 4; ++kk) bc[kk] = *(const short8*)(bp + kk * 512);
    }
    while (true) {
      const int wtn = wt + stride;
      const bool more = wtn < cnt;
      short8 bn[4];
      if (more) {
        const unsigned short* bp = Bblk + (size_t)wtn * 2048 + lane * 8;
        #pragma unroll
        for (int kk = 0; kk < 4; ++kk) bn[kk] = *(const short8*)(bp + kk * 512);
      }
      #pragma unroll
      for (int rg = 0; rg < 4; ++rg) {
        float4v C = {0.f, 0.f, 0.f, 0.f};
        #pragma unroll
        for (int kk = 0; kk < 4; ++kk)
          C = __builtin_amdgcn_mfma_f32_16x16x32_bf16(a[rg][kk], bc[kk], C, 0, 0, 0);
        #pragma unroll
        for (int r = 0; r < 4; ++r) {
          float d = C[r];
          float e = EXP2(fmaf(d, TWO_LOG2E, -TWO_LOG2E));
          ae[rg][r] += e;
          ade[rg][r] = fmaf(d, e, ade[rg][r]);
        }
      }
      if (!more) break;
      wt = wtn;
      #pragma unroll
      for (int kk = 0; kk < 4; ++kk) bc[kk] = bn[kk];
    }
  }
  #pragma unroll
  for (int rg = 0; rg < 4; ++rg)
    #pragma unroll
    for (int r = 0; r < 4; ++r) {
      float e = ae[rg][r], de = ade[rg][r];
      #pragma unroll
      for (int mk = 8; mk >= 1; mk >>= 1) {
        e  += __shfl_xor(e,  mk, 64);
        de += __shfl_xor(de, mk, 64);
      }
      if (m == 0) {
        int row = rowBase + rg * 16 + quad * 4 + r;
        atomicAdd(&acc_e[row],  e);
        atomicAdd(&acc_ce[row], 2.f * (e - de));
      }
    }
}

// fallback intra (4-rg) + loss1
__global__ __launch_bounds__(256) void mfma_intra(
    const float* __restrict__ q, float* __restrict__ ws) {
  const int x  = (int)blockIdx.z;
  const int yg = (int)blockIdx.y;
  const float* qx = q + (size_t)x * NROWS * DDIM;
  const int lane = (int)threadIdx.x & 63;
  const int wave = (int)threadIdx.x >> 6;
  const int quad = lane >> 4;
  const int m    = lane & 15;
  const int rowBase = (int)blockIdx.x * 64;

  __shared__ float l_e[4][64], l_de[4][64];

  short8 a[4][4];
  #pragma unroll
  for (int rg = 0; rg < 4; ++rg)
    #pragma unroll
    for (int kk = 0; kk < 4; ++kk)
      a[rg][kk] = cvt8(qx + (size_t)(rowBase + rg * 16 + m) * DDIM + kk * 32 + quad * 8);

  float ae[4][4] = {}, ade[4][4] = {};
  for (int jt = yg * 4 + wave; jt < NROWS / 16; jt += 32) {
    short8 bfr[4];
    #pragma unroll
    for (int kk = 0; kk < 4; ++kk)
      bfr[kk] = cvt8(qx + (size_t)(jt * 16 + m) * DDIM + kk * 32 + quad * 8);
    const int dgRg = (jt * 16 - rowBase) >> 4;
    #pragma unroll
    for (int rg = 0; rg < 4; ++rg) {
      float4v C = {0.f, 0.f, 0.f, 0.f};
      #pragma unroll
      for (int kk = 0; kk < 4; ++kk)
        C = __builtin_amdgcn_mfma_f32_16x16x32_bf16(a[rg][kk], bfr[kk], C, 0, 0, 0);
      #pragma unroll
      for (int r = 0; r < 4; ++r) {
        float d = C[r];
        float e = EXP2(fmaf(d, TWO_LOG2E, -TWO_LOG2E));
        float de = d * e;
        if (rg == dgRg && (quad * 4 + r) == m) { e = 0.f; de = 0.f; }
        ae[rg][r] += e;
        ade[rg][r] += de;
      }
    }
  }
  #pragma unroll
  for (int rg = 0; rg < 4; ++rg)
    #pragma unroll
    for (int r = 0; r < 4; ++r) {
      float e = ae[rg][r], de = ade[rg][r];
      #pragma unroll
      for (int mk = 8; mk >= 1; mk >>= 1) {
        e  += __shfl_xor(e,  mk, 64);
        de += __shfl_xor(de, mk, 64);
      }
      if (m == 0) {
        l_e[wave][rg * 16 + quad * 4 + r]  = e;
        l_de[wave][rg * 16 + quad * 4 + r] = de;
      }
    }
  __syncthreads();
  const int tid = (int)threadIdx.x;
  if (tid < 64) {
    float E = l_e[0][tid] + l_e[1][tid] + l_e[2][tid] + l_e[3][tid];
    float D = l_de[0][tid] + l_de[1][tid] + l_de[2][tid] + l_de[3][tid];
    const int slot = x * 8 + yg;
    ws[IPART + (size_t)slot * 2048 + rowBase + tid]        = E;
    ws[IPART + (size_t)slot * 2048 + 1024 + rowBase + tid] = D;
  }
}

__global__ void loss1_k(const float* __restrict__ q, const float* __restrict__ k,
                        float* __restrict__ l1part) {
  int gw   = (int)(blockIdx.x * blockDim.x + threadIdx.x) >> 6;
  int lane = (int)threadIdx.x & 63;
  int x = gw >> 10;
  int i = gw & 1023;
  const float2* qp = (const float2*)(q + (size_t)(x * NROWS + i) * DDIM);
  const float2* kp = (const float2*)(k + (size_t)((1 - x) * NROWS + i) * DDIM);
  float2 a = qp[lane];
  float2 b = kp[lane];
  float s = wave_sum(a.x * b.x + a.y * b.y);
  if (lane == 0) l1part[gw] = s;
}

extern "C" void kernel_launch(void* const* d_in, const int* in_sizes, int n_in,
                              void* d_out, int out_size, void* d_ws, size_t ws_size,
                              hipStream_t stream) {
  const float* q     = (const float*)d_in[0];   // [2][1024][128]
  const float* k     = (const float*)d_in[1];   // [2][1024][128]
  const float* queue = (const float*)d_in[2];   // [128][65536]
  float* ws  = (float*)d_ws;
  float* out = (float*)d_out;
  unsigned short* Bblk = (unsigned short*)((char*)d_ws + BBLK_BYTE_OFF);

  const size_t needFull = BBLK_BYTE_OFF + (size_t)NTILE * 4096;   // 2MB hdr + 16MB
  if (ws_size >= needFull) {
    hipLaunchKernelGGL(prep_k, dim3(PREP_TOTAL), dim3(256), 0, stream,
                       queue, q, k, Bblk, ws);
    hipLaunchKernelGGL(megaq_k, dim3(2048), dim3(256), 0, stream, q, Bblk, ws);
    hipLaunchKernelGGL(final2_k, dim3(1), dim3(256), 0, stream, ws, out);
  } else {
    // fallback: chunked queue path with atomics into QS (zeroed first)
    unsigned short* Bsmall = (unsigned short*)((char*)d_ws + 512 * 1024);
    hipLaunchKernelGGL(zero_ws, dim3(8), dim3(256), 0, stream, ws);
    hipLaunchKernelGGL(mfma_intra, dim3(16, 8, 2), dim3(256), 0, stream, q, ws);
    hipLaunchKernelGGL(loss1_k, dim3(512), dim3(256), 0, stream, q, k, ws + 6144);
    size_t avail = (ws_size > 512 * 1024) ? (ws_size - 512 * 1024) : 16384;
    int maxJt = (int)(avail / 4096);
    maxJt &= ~3;
    if (maxJt > NTILE) maxJt = NTILE;
    if (maxJt < 4) maxJt = 4;
    int nch = (NTILE + maxJt - 1) / maxJt;
    for (int c = 0; c < nch; ++c) {
      int jt0  = c * maxJt;
      int cntc = NTILE - jt0; if (cntc > maxJt) cntc = maxJt;
      hipLaunchKernelGGL(conv_B_ck, dim3(cntc / 4), dim3(256), 0, stream,
                         queue, Bsmall, jt0 * 16);
      int gy = (cntc + 3) / 4; if (gy > 64) gy = 64;
      hipLaunchKernelGGL(mfma_queue_ck, dim3(16, gy), dim3(256), 0, stream,
                         q, Bsmall, cntc, ws, ws + 1024);
    }
    hipLaunchKernelGGL(final2_k, dim3(1), dim3(256), 0, stream, ws, out);
  }
}

// Round 8
// 147.256 us; speedup vs baseline: 1.0287x; 1.0287x over previous
//
#include <hip/hip_runtime.h>
#include <hip/hip_bf16.h>

// MoCo loss on MI355X. V=2, N=1024, D=128, K=65536, fp32 in, 2 fp32 scalars out.
// R16: 3 launches:
//   conv_k  (1024): queue fp32 -> Bblk bf16 tiles (LDS transpose, verified);
//                   blocks 0-7 zero QS.
//   mega_k  (1568): intra [0,512) | loss1 [512,544) | queue-4rg [544,1568).
//                   Queue: 64 rows/block (a[4][4]), 16 MFMA per 4KB tile
//                   (64 FLOP/B, 2x R15), R13 runtime-bounded no-barrier loop,
//                   1-deep prefetch. Small blocks dispatch first and hide
//                   under queue blocks (R6 trick; R15 serialized them = +17us).
//   final3_k (1x1024): IPart reduce + loss2 + loss1 fold, 16 waves.
// Lessons: R12 compile-time trip -> unroll -> 180 VGPR. R13 2x occupancy = 0.
// R14 LDS+barrier/iter = worse. R15 2x MLP = 0. -> raise FLOP/B, keep shape.
//
// loss2 row sums: den += exp(-c), num += c*exp(-c), c = 2-2*dot.
// QS atomics: ws[row] += Se, ws[1024+row] += 2*(Se-Sde).
//
// ws floats:
//   [0,2048)        QS_e[1024], QS_ce[1024]     (atomic accum)
//   [6144,8192)     l1part[2048]
//   [139264,172032) IPart[16][2][1024]   slot = x*8+yg
//   byte 2 MB+:     Bblk (bf16, 16 MB)
//
// MFMA 16x16x32 bf16: A[m=lane&15][k=quad*8+j]; B[k=quad*8+j][n=lane&15];
// C: col=lane&15, row=quad*4+reg.

#define NROWS 1024
#define DDIM  128
#define KQ    65536
#define NTILE 4096          // 65536/16 col-tiles
#define SLICE 512           // tiles per XCD slice (512*4KB = 2MB)
#define SUB   8
#define IPART 139264
#define BBLK_BYTE_OFF (2u*1024u*1024u)
#define TWO_LOG2E 2.8853900817779268f

#define MB_INTRA 512
#define MB_L1    544
#define MB_TOTAL (MB_L1 + 1024)   // queue offset 544 % 8 == 0 keeps swizzle

typedef __attribute__((ext_vector_type(8))) short  short8;
typedef __attribute__((ext_vector_type(4))) float  float4v;

#if __has_builtin(__builtin_amdgcn_exp2f)
#define EXP2(x) __builtin_amdgcn_exp2f(x)
#else
#define EXP2(x) __expf((x) * 0.6931471805599453f)
#endif

__device__ __forceinline__ unsigned short f2bf(float f) {
  unsigned u = __float_as_uint(f);
  u += 0x7FFF + ((u >> 16) & 1);           // RNE
  return (unsigned short)(u >> 16);
}

__device__ __forceinline__ short8 cvt8(const float* __restrict__ p) {
  float4 a = *(const float4*)p;
  float4 b = *(const float4*)(p + 4);
  short8 r;
  r[0] = (short)f2bf(a.x); r[1] = (short)f2bf(a.y);
  r[2] = (short)f2bf(a.z); r[3] = (short)f2bf(a.w);
  r[4] = (short)f2bf(b.x); r[5] = (short)f2bf(b.y);
  r[6] = (short)f2bf(b.z); r[7] = (short)f2bf(b.w);
  return r;
}

__device__ __forceinline__ float wave_sum(float v) {
  #pragma unroll
  for (int o = 32; o > 0; o >>= 1) v += __shfl_down(v, o, 64);
  return v;
}

__global__ void zero_ws(float* __restrict__ ws) {
  ws[blockIdx.x * 256 + threadIdx.x] = 0.f;   // fallback only
}

// ---------- conv_k: queue [128][65536] fp32 -> Bblk tiles, XCD-sliced ----

__global__ __launch_bounds__(256) void conv_k(
    const float* __restrict__ queue, unsigned short* __restrict__ Bblk,
    float* __restrict__ ws) {
  __shared__ float lf[128][65];
  const int b   = (int)blockIdx.x;          // 0..1023
  const int tid = (int)threadIdx.x;
  if (b < 8) ws[b * 256 + tid] = 0.f;       // zero QS region
  const int xcd   = b & 7;
  const int idx   = b >> 3;                 // 0..127
  const int c0    = xcd * (SLICE * 16) + idx * 64;
  const int tile0 = xcd * SLICE + idx * 4;

  const int rl = tid >> 4;                  // 0..15
  const int cl = (tid & 15) * 4;            // 0..60
  #pragma unroll
  for (int p = 0; p < 8; ++p) {
    const int d = p * 16 + rl;
    float4 v = *(const float4*)(queue + (size_t)d * KQ + c0 + cl);
    lf[d][cl + 0] = v.x; lf[d][cl + 1] = v.y;
    lf[d][cl + 2] = v.z; lf[d][cl + 3] = v.w;
  }
  __syncthreads();
  #pragma unroll
  for (int s = 0; s < 4; ++s) {
    const int kk2  = tid >> 6;              // 0..3
    const int e8   = tid & 63;              // quad*16+n
    const int q2   = e8 >> 4, n = e8 & 15;
    const int dbase = kk2 * 32 + q2 * 8;
    const int col   = s * 16 + n;
    short8 sv;
    #pragma unroll
    for (int j = 0; j < 8; ++j) sv[j] = (short)f2bf(lf[dbase + j][col]);
    *(short8*)(Bblk + ((size_t)(tile0 + s) * 4 + kk2) * 512 + e8 * 8) = sv;
  }
}

// ---------- mega: intra [0,512) | loss1 [512,544) | queue-4rg [544,1568) ----

__global__ __launch_bounds__(256) void mega_k(
    const float* __restrict__ q, const float* __restrict__ kin,
    const unsigned short* __restrict__ Bblk, float* __restrict__ ws) {
  __shared__ float l_e[4][32], l_de[4][32];
  const int b    = (int)blockIdx.x;
  const int tid  = (int)threadIdx.x;
  const int lane = tid & 63;
  const int wave = tid >> 6;
  const int quad = lane >> 4;
  const int m    = lane & 15;

  if (b >= MB_L1) {
    // ---- queue GEMM, 4 row-groups (64 rows/block), 16 MFMA per 4KB tile.
    const int fb     = b - MB_L1;             // 0..1023
    const int xcd    = fb & 7;
    const int t      = fb >> 3;               // 0..127
    const int rowblk = t & 15;                // 16 x 64 rows
    const int sub    = t >> 4;                // 0..7
    const int rowBase = rowblk * 64;

    short8 a[4][4];
    #pragma unroll
    for (int rg = 0; rg < 4; ++rg)
      #pragma unroll
      for (int kk = 0; kk < 4; ++kk)
        a[rg][kk] = cvt8(q + (size_t)(rowBase + rg * 16 + m) * DDIM + kk * 32 + quad * 8);

    float ae[4][4] = {}, ade[4][4] = {};

    int wt = xcd * SLICE + sub * 4 + wave;    // 16 tiles/wave, stride 32
    const int wtEnd = (xcd + 1) * SLICE;
    short8 bc[4];
    {
      const unsigned short* bp = Bblk + (size_t)wt * 2048 + lane * 8;
      #pragma unroll
      for (int kk = 0; kk < 4; ++kk) bc[kk] = *(const short8*)(bp + kk * 512);
    }
    while (true) {
      const int wtn = wt + SUB * 4;
      const bool more = wtn < wtEnd;
      short8 bn[4];
      if (more) {
        const unsigned short* bp = Bblk + (size_t)wtn * 2048 + lane * 8;
        #pragma unroll
        for (int kk = 0; kk < 4; ++kk) bn[kk] = *(const short8*)(bp + kk * 512);
      }
      #pragma unroll
      for (int rg = 0; rg < 4; ++rg) {
        float4v C = {0.f, 0.f, 0.f, 0.f};
        #pragma unroll
        for (int kk = 0; kk < 4; ++kk)
          C = __builtin_amdgcn_mfma_f32_16x16x32_bf16(a[rg][kk], bc[kk], C, 0, 0, 0);
        #pragma unroll
        for (int r = 0; r < 4; ++r) {
          float d = C[r];
          float e = EXP2(fmaf(d, TWO_LOG2E, -TWO_LOG2E));
          ae[rg][r] += e;
          ade[rg][r] = fmaf(d, e, ade[rg][r]);
        }
      }
      if (!more) break;
      wt = wtn;
      #pragma unroll
      for (int kk = 0; kk < 4; ++kk) bc[kk] = bn[kk];
    }

    // all 4 waves cover the same 64 rows over disjoint tiles -> atomics
    #pragma unroll
    for (int rg = 0; rg < 4; ++rg)
      #pragma unroll
      for (int r = 0; r < 4; ++r) {
        float e = ae[rg][r], de = ade[rg][r];
        #pragma unroll
        for (int mk = 8; mk >= 1; mk >>= 1) {
          e  += __shfl_xor(e,  mk, 64);
          de += __shfl_xor(de, mk, 64);
        }
        if (m == 0) {
          const int row = rowBase + rg * 16 + quad * 4 + r;
          atomicAdd(&ws[row],        e);
          atomicAdd(&ws[1024 + row], 2.f * (e - de));
        }
      }
  } else if (b < MB_INTRA) {
    // ---- intra 2-rg (verified): b = rowblk | yg<<5 | x<<8
    const int rowblk = b & 31;
    const int yg = (b >> 5) & 7;
    const int x  = b >> 8;
    const float* qx = q + (size_t)x * NROWS * DDIM;
    const int rowBase = rowblk * 32;

    short8 a[2][4];
    #pragma unroll
    for (int rg = 0; rg < 2; ++rg)
      #pragma unroll
      for (int kk = 0; kk < 4; ++kk)
        a[rg][kk] = cvt8(qx + (size_t)(rowBase + rg * 16 + m) * DDIM + kk * 32 + quad * 8);

    float ae[2][4] = {}, ade[2][4] = {};
    for (int jt = yg * 4 + wave; jt < NROWS / 16; jt += 32) {
      short8 bfr[4];
      #pragma unroll
      for (int kk = 0; kk < 4; ++kk)
        bfr[kk] = cvt8(qx + (size_t)(jt * 16 + m) * DDIM + kk * 32 + quad * 8);
      const int dgRg = (jt * 16 - rowBase) >> 4;
      #pragma unroll
      for (int rg = 0; rg < 2; ++rg) {
        float4v C = {0.f, 0.f, 0.f, 0.f};
        #pragma unroll
        for (int kk = 0; kk < 4; ++kk)
          C = __builtin_amdgcn_mfma_f32_16x16x32_bf16(a[rg][kk], bfr[kk], C, 0, 0, 0);
        #pragma unroll
        for (int r = 0; r < 4; ++r) {
          float d = C[r];
          float e = EXP2(fmaf(d, TWO_LOG2E, -TWO_LOG2E));
          float de = d * e;
          if (rg == dgRg && (quad * 4 + r) == m) { e = 0.f; de = 0.f; }
          ae[rg][r] += e;
          ade[rg][r] += de;
        }
      }
    }
    #pragma unroll
    for (int rg = 0; rg < 2; ++rg)
      #pragma unroll
      for (int r = 0; r < 4; ++r) {
        float e = ae[rg][r], de = ade[rg][r];
        #pragma unroll
        for (int mk = 8; mk >= 1; mk >>= 1) {
          e  += __shfl_xor(e,  mk, 64);
          de += __shfl_xor(de, mk, 64);
        }
        if (m == 0) {
          l_e[wave][rg * 16 + quad * 4 + r]  = e;
          l_de[wave][rg * 16 + quad * 4 + r] = de;
        }
      }
    __syncthreads();
    if (tid < 32) {
      float E = l_e[0][tid] + l_e[1][tid] + l_e[2][tid] + l_e[3][tid];
      float D = l_de[0][tid] + l_de[1][tid] + l_de[2][tid] + l_de[3][tid];
      const int slot = x * 8 + yg;
      ws[IPART + (size_t)slot * 2048 + rowBase + tid]        = E;
      ws[IPART + (size_t)slot * 2048 + 1024 + rowBase + tid] = D;
    }
  } else {
    // ---- loss1 (verified): wave handles 16 (x,i) rows
    const int gw0 = (b - MB_INTRA) * 4 + wave;   // 0..127
    for (int t = 0; t < 16; ++t) {
      const int idx = gw0 * 16 + t;              // 0..2047
      const int x = idx >> 10;
      const int i = idx & 1023;
      const float2* qp = (const float2*)(q + (size_t)(x * NROWS + i) * DDIM);
      const float2* kp = (const float2*)(kin + (size_t)((1 - x) * NROWS + i) * DDIM);
      float2 av = qp[lane];
      float2 bv = kp[lane];
      float s = wave_sum(av.x * bv.x + av.y * bv.y);
      if (lane == 0) ws[6144 + idx] = s;
    }
  }
}

// ---------- final3: IPart reduce + loss2 + loss1 fold, 1024 threads ----------

__global__ __launch_bounds__(1024) void final3_k(const float* __restrict__ ws,
                                                 float* __restrict__ out) {
  const float* l1part = ws + 6144;
  __shared__ float red1[1024], red2[1024];
  const int tid = (int)threadIdx.x;
  float p1 = 0.f, p2 = 0.f;
  for (int idx = tid; idx < 2048; idx += 1024) {
    int x = idx >> 10;
    int i = idx & 1023;
    p1 += 2.f - 2.f * l1part[idx];
    float E = 0.f, D = 0.f;
    #pragma unroll
    for (int g = 0; g < 8; ++g) {
      const int s = x * 8 + g;
      E += ws[IPART + (size_t)s * 2048 + i];
      D += ws[IPART + (size_t)s * 2048 + 1024 + i];
    }
    float den = ws[i]        + E;
    float num = ws[1024 + i] + 2.f * (E - D);
    p2 += num / den;
  }
  red1[tid] = p1;
  red2[tid] = p2;
  __syncthreads();
  for (int s = 512; s > 0; s >>= 1) {
    if (tid < s) {
      red1[tid] += red1[tid + s];
      red2[tid] += red2[tid + s];
    }
    __syncthreads();
  }
  if (tid == 0) {
    out[0] = red1[0] * (1.f / (2.f * NROWS));
    out[1] = -red2[0] * (1.f / (2.f * NROWS));
  }
}

// ---------- chunked fallback (ws too small for full Bblk) ----------

__global__ void conv_B_ck(const float* __restrict__ queue,
                          unsigned short* __restrict__ Bblk, int c0chunk) {
  const int tid  = (int)threadIdx.x;
  const int g    = tid >> 4;
  const int ci   = (tid & 15) * 4;
  const int cloc = (int)blockIdx.x * 64 + ci;
  const int c    = c0chunk + cloc;
  const int d0   = g * 8;
  const int kk   = g >> 2;
  const int quad = g & 3;
  float4v v[8];
  #pragma unroll
  for (int dd = 0; dd < 8; ++dd)
    v[dd] = *(const float4v*)(queue + (size_t)(d0 + dd) * KQ + c);
  unsigned short* outp = Bblk + ((size_t)(cloc >> 4) * 4 + kk) * 512
                              + (quad * 16 + (cloc & 15)) * 8;
  #pragma unroll
  for (int n = 0; n < 4; ++n) {
    short8 s;
    #pragma unroll
    for (int dd = 0; dd < 8; ++dd)
      s[dd] = (short)f2bf(v[dd][n]);
    *(short8*)(outp + n * 8) = s;
  }
}

__global__ __launch_bounds__(256) void mfma_queue_ck(
    const float* __restrict__ q, const unsigned short* __restrict__ Bblk,
    int cnt, float* __restrict__ acc_e, float* __restrict__ acc_ce) {
  const int lane = (int)threadIdx.x & 63;
  const int wave = (int)threadIdx.x >> 6;
  const int quad = lane >> 4;
  const int m    = lane & 15;
  const int rowBase = (int)blockIdx.x * 64;

  short8 a[4][4];
  #pragma unroll
  for (int rg = 0; rg < 4; ++rg)
    #pragma unroll
    for (int kk = 0; kk < 4; ++kk)
      a[rg][kk] = cvt8(q + (size_t)(rowBase + rg * 16 + m) * DDIM + kk * 32 + quad * 8);

  float ae[4][4] = {}, ade[4][4] = {};
  const int stride = (int)gridDim.y * 4;
  int wt = (int)blockIdx.y * 4 + wave;
  if (wt < cnt) {
    short8 bc[4];
    {
      const unsigned short* bp = Bblk + (size_t)wt * 2048 + lane * 8;
      #pragma unroll
      for (int kk = 0; kk < 4; ++kk) bc[kk] = *(const short8*)(bp + kk * 512);
    }
    while (true) {
      const int wtn = wt + stride;
      const bool more = wtn < cnt;
      short8 bn[4];
      if (more) {
        const unsigned short* bp = Bblk + (size_t)wtn * 2048 + lane * 8;
        #pragma unroll
        for (int kk = 0; kk < 4; ++kk) bn[kk] = *(const short8*)(bp + kk * 512);
      }
      #pragma unroll
      for (int rg = 0; rg < 4; ++rg) {
        float4v C = {0.f, 0.f, 0.f, 0.f};
        #pragma unroll
        for (int kk = 0; kk < 4; ++kk)
          C = __builtin_amdgcn_mfma_f32_16x16x32_bf16(a[rg][kk], bc[kk], C, 0, 0, 0);
        #pragma unroll
        for (int r = 0; r < 4; ++r) {
          float d = C[r];
          float e = EXP2(fmaf(d, TWO_LOG2E, -TWO_LOG2E));
          ae[rg][r] += e;
          ade[rg][r] = fmaf(d, e, ade[rg][r]);
        }
      }
      if (!more) break;
      wt = wtn;
      #pragma unroll
      for (int kk = 0; kk < 4; ++kk) bc[kk] = bn[kk];
    }
  }
  #pragma unroll
  for (int rg = 0; rg < 4; ++rg)
    #pragma unroll
    for (int r = 0; r < 4; ++r) {
      float e = ae[rg][r], de = ade[rg][r];
      #pragma unroll
      for (int mk = 8; mk >= 1; mk >>= 1) {
        e  += __shfl_xor(e,  mk, 64);
        de += __shfl_xor(de, mk, 64);
      }
      if (m == 0) {
        int row = rowBase + rg * 16 + quad * 4 + r;
        atomicAdd(&acc_e[row],  e);
        atomicAdd(&acc_ce[row], 2.f * (e - de));
      }
    }
}

// fallback intra (4-rg) + loss1
__global__ __launch_bounds__(256) void mfma_intra(
    const float* __restrict__ q, float* __restrict__ ws) {
  const int x  = (int)blockIdx.z;
  const int yg = (int)blockIdx.y;
  const float* qx = q + (size_t)x * NROWS * DDIM;
  const int lane = (int)threadIdx.x & 63;
  const int wave = (int)threadIdx.x >> 6;
  const int quad = lane >> 4;
  const int m    = lane & 15;
  const int rowBase = (int)blockIdx.x * 64;

  __shared__ float l_e[4][64], l_de[4][64];

  short8 a[4][4];
  #pragma unroll
  for (int rg = 0; rg < 4; ++rg)
    #pragma unroll
    for (int kk = 0; kk < 4; ++kk)
      a[rg][kk] = cvt8(qx + (size_t)(rowBase + rg * 16 + m) * DDIM + kk * 32 + quad * 8);

  float ae[4][4] = {}, ade[4][4] = {};
  for (int jt = yg * 4 + wave; jt < NROWS / 16; jt += 32) {
    short8 bfr[4];
    #pragma unroll
    for (int kk = 0; kk < 4; ++kk)
      bfr[kk] = cvt8(qx + (size_t)(jt * 16 + m) * DDIM + kk * 32 + quad * 8);
    const int dgRg = (jt * 16 - rowBase) >> 4;
    #pragma unroll
    for (int rg = 0; rg < 4; ++rg) {
      float4v C = {0.f, 0.f, 0.f, 0.f};
      #pragma unroll
      for (int kk = 0; kk < 4; ++kk)
        C = __builtin_amdgcn_mfma_f32_16x16x32_bf16(a[rg][kk], bfr[kk], C, 0, 0, 0);
      #pragma unroll
      for (int r = 0; r < 4; ++r) {
        float d = C[r];
        float e = EXP2(fmaf(d, TWO_LOG2E, -TWO_LOG2E));
        float de = d * e;
        if (rg == dgRg && (quad * 4 + r) == m) { e = 0.f; de = 0.f; }
        ae[rg][r] += e;
        ade[rg][r] += de;
      }
    }
  }
  #pragma unroll
  for (int rg = 0; rg < 4; ++rg)
    #pragma unroll
    for (int r = 0; r < 4; ++r) {
      float e = ae[rg][r], de = ade[rg][r];
      #pragma unroll
      for (int mk = 8; mk >= 1; mk >>= 1) {
        e  += __shfl_xor(e,  mk, 64);
        de += __shfl_xor(de, mk, 64);
      }
      if (m == 0) {
        l_e[wave][rg * 16 + quad * 4 + r]  = e;
        l_de[wave][rg * 16 + quad * 4 + r] = de;
      }
    }
  __syncthreads();
  const int tid = (int)threadIdx.x;
  if (tid < 64) {
    float E = l_e[0][tid] + l_e[1][tid] + l_e[2][tid] + l_e[3][tid];
    float D = l_de[0][tid] + l_de[1][tid] + l_de[2][tid] + l_de[3][tid];
    const int slot = x * 8 + yg;
    ws[IPART + (size_t)slot * 2048 + rowBase + tid]        = E;
    ws[IPART + (size_t)slot * 2048 + 1024 + rowBase + tid] = D;
  }
}

__global__ void loss1_k(const float* __restrict__ q, const float* __restrict__ k,
                        float* __restrict__ l1part) {
  int gw   = (int)(blockIdx.x * blockDim.x + threadIdx.x) >> 6;
  int lane = (int)threadIdx.x & 63;
  int x = gw >> 10;
  int i = gw & 1023;
  const float2* qp = (const float2*)(q + (size_t)(x * NROWS + i) * DDIM);
  const float2* kp = (const float2*)(k + (size_t)((1 - x) * NROWS + i) * DDIM);
  float2 a = qp[lane];
  float2 b = kp[lane];
  float s = wave_sum(a.x * b.x + a.y * b.y);
  if (lane == 0) l1part[gw] = s;
}

extern "C" void kernel_launch(void* const* d_in, const int* in_sizes, int n_in,
                              void* d_out, int out_size, void* d_ws, size_t ws_size,
                              hipStream_t stream) {
  const float* q     = (const float*)d_in[0];   // [2][1024][128]
  const float* k     = (const float*)d_in[1];   // [2][1024][128]
  const float* queue = (const float*)d_in[2];   // [128][65536]
  float* ws  = (float*)d_ws;
  float* out = (float*)d_out;
  unsigned short* Bblk = (unsigned short*)((char*)d_ws + BBLK_BYTE_OFF);

  const size_t needFull = BBLK_BYTE_OFF + (size_t)NTILE * 4096;   // 2MB hdr + 16MB
  if (ws_size >= needFull) {
    hipLaunchKernelGGL(conv_k, dim3(1024), dim3(256), 0, stream, queue, Bblk, ws);
    hipLaunchKernelGGL(mega_k, dim3(MB_TOTAL), dim3(256), 0, stream,
                       q, k, Bblk, ws);
    hipLaunchKernelGGL(final3_k, dim3(1), dim3(1024), 0, stream, ws, out);
  } else {
    // fallback: chunked queue path with atomics into QS (zeroed first)
    unsigned short* Bsmall = (unsigned short*)((char*)d_ws + 512 * 1024);
    hipLaunchKernelGGL(zero_ws, dim3(8), dim3(256), 0, stream, ws);
    hipLaunchKernelGGL(mfma_intra, dim3(16, 8, 2), dim3(256), 0, stream, q, ws);
    hipLaunchKernelGGL(loss1_k, dim3(512), dim3(256), 0, stream, q, k, ws + 6144);
    size_t avail = (ws_size > 512 * 1024) ? (ws_size - 512 * 1024) : 16384;
    int maxJt = (int)(avail / 4096);
    maxJt &= ~3;
    if (maxJt > NTILE) maxJt = NTILE;
    if (maxJt < 4) maxJt = 4;
    int nch = (NTILE + maxJt - 1) / maxJt;
    for (int c = 0; c < nch; ++c) {
      int jt0  = c * maxJt;
      int cntc = NTILE - jt0; if (cntc > maxJt) cntc = maxJt;
      hipLaunchKernelGGL(conv_B_ck, dim3(cntc / 4), dim3(256), 0, stream,
                         queue, Bsmall, jt0 * 16);
      int gy = (cntc + 3) / 4; if (gy > 64) gy = 64;
      hipLaunchKernelGGL(mfma_queue_ck, dim3(16, gy), dim3(256), 0, stream,
                         q, Bsmall, cntc, ws, ws + 1024);
    }
    hipLaunchKernelGGL(final3_k, dim3(1), dim3(1024), 0, stream, ws, out);
  }
}

// Round 9
// 127.670 us; speedup vs baseline: 1.1865x; 1.1534x over previous
//
#include <hip/hip_runtime.h>
#include <hip/hip_bf16.h>

// MoCo loss on MI355X. V=2, N=1024, D=128, K=65536, fp32 in, 2 fp32 scalars out.
// R17: decode-the-remainder round.
//   conv_k (512): 128col x 128d windows; phase1 contiguous 512B row-segment
//     loads -> f2bf -> LDS [128][140] ushort (8B writes); phase2 exact Bblk
//     chunks (one 16B store/lane). Blocks 0-7 zero QS.
//   mega_k (1568): intra [0,512) | loss1 [512,544) | queue-R2-EXACT [544,1568)
//     (2-rg, SUB=4, 32 iters, runtime-bounded 1-deep prefetch = 51.5us/56VGPR
//     anchor) with atomic finish (R15: atomics don't move the plateau).
//   final3_k (1x1024): IPart reduce + loss2 + loss1 fold.
// Evidence: total-mega = 91..99us with scatter conv, 62 with R16 LDS conv ->
// remainder is REAL conv time (~50us, ~0.6TB/s). Fix DRAM granularity.
// Queue-loop family exhausted: 51.5 (R2) / 55.6 (SUB8) / 60 (LDS+barrier) /
// 52 (2-deep) / 85 (4-rg). 334 TF == guide ladder step-0 for this structure.
//
// loss2 row sums: den += exp(-c), num += c*exp(-c), c = 2-2*dot.
// QS atomics: ws[row] += Se, ws[1024+row] += 2*(Se-Sde).
//
// ws floats:
//   [0,2048)        QS_e[1024], QS_ce[1024]   (atomic accum)
//   [6144,8192)     l1part[2048]
//   [139264,172032) IPart[16][2][1024]  slot = x*8+yg
//   byte 2 MB+:     Bblk (bf16, 16 MB)
//
// MFMA 16x16x32 bf16: A[m=lane&15][k=quad*8+j]; B[k=quad*8+j][n=lane&15];
// C: col=lane&15, row=quad*4+reg.
// Bblk[(tile*4+kk)*512 + (quad*16+n)*8 + j] = bf16(queue[kk*32+quad*8+j][tile*16+n])

#define NROWS 1024
#define DDIM  128
#define KQ    65536
#define NTILE 4096
#define SLICE 512           // tiles per XCD slice
#define SUB   4
#define IPART 139264
#define BBLK_BYTE_OFF (2u*1024u*1024u)
#define TWO_LOG2E 2.8853900817779268f

#define MB_INTRA 512
#define MB_L1    544
#define MB_TOTAL (MB_L1 + 1024)

typedef __attribute__((ext_vector_type(8))) short  short8;
typedef __attribute__((ext_vector_type(4))) float  float4v;

#if __has_builtin(__builtin_amdgcn_exp2f)
#define EXP2(x) __builtin_amdgcn_exp2f(x)
#else
#define EXP2(x) __expf((x) * 0.6931471805599453f)
#endif

__device__ __forceinline__ unsigned short f2bf(float f) {
  unsigned u = __float_as_uint(f);
  u += 0x7FFF + ((u >> 16) & 1);           // RNE
  return (unsigned short)(u >> 16);
}

__device__ __forceinline__ short8 cvt8(const float* __restrict__ p) {
  float4 a = *(const float4*)p;
  float4 b = *(const float4*)(p + 4);
  short8 r;
  r[0] = (short)f2bf(a.x); r[1] = (short)f2bf(a.y);
  r[2] = (short)f2bf(a.z); r[3] = (short)f2bf(a.w);
  r[4] = (short)f2bf(b.x); r[5] = (short)f2bf(b.y);
  r[6] = (short)f2bf(b.z); r[7] = (short)f2bf(b.w);
  return r;
}

__device__ __forceinline__ float wave_sum(float v) {
  #pragma unroll
  for (int o = 32; o > 0; o >>= 1) v += __shfl_down(v, o, 64);
  return v;
}

__global__ void zero_ws(float* __restrict__ ws) {
  ws[blockIdx.x * 256 + threadIdx.x] = 0.f;   // fallback only
}

// ---------- conv_k: 512 blocks, 128col x 128d window each ----------

__global__ __launch_bounds__(256) void conv_k(
    const float* __restrict__ queue, unsigned short* __restrict__ Bblk,
    float* __restrict__ ws) {
  __shared__ unsigned short lsh[128][140];   // 35.8 KB, stride 140 (8B-aligned)
  const int b   = (int)blockIdx.x;           // 0..511
  const int tid = (int)threadIdx.x;
  if (b < 8) ws[b * 256 + tid] = 0.f;        // zero QS region
  const int xcd   = b & 7;
  const int w     = b >> 3;                  // 0..63
  const int c0    = xcd * 8192 + w * 128;
  const int tile0 = xcd * SLICE + w * 8;

  // phase 1: rows (tid>>5)+8s, cols (tid&31)*4 -> 512B contiguous per 32 lanes
  const int r0 = tid >> 5;                   // 0..7
  const int cc = (tid & 31) * 4;             // 0..124
  #pragma unroll
  for (int s = 0; s < 16; ++s) {
    const int r = r0 + s * 8;
    float4 v = *(const float4*)(queue + (size_t)r * KQ + c0 + cc);
    unsigned short u0 = f2bf(v.x), u1 = f2bf(v.y), u2 = f2bf(v.z), u3 = f2bf(v.w);
    *(ushort4*)(&lsh[r][cc]) = make_ushort4(u0, u1, u2, u3);
  }
  __syncthreads();

  // phase 2: 32 chunks (tl 0..7, kk 0..3); wave handles 8
  const int lane = tid & 63;
  const int wave = tid >> 6;
  const int quad = lane >> 4;
  const int n    = lane & 15;
  #pragma unroll
  for (int s2 = 0; s2 < 8; ++s2) {
    const int chunk = wave * 8 + s2;
    const int tl = chunk >> 2;
    const int kk = chunk & 3;
    const int dbase = kk * 32 + quad * 8;
    const int col   = tl * 16 + n;
    short8 sv;
    #pragma unroll
    for (int j = 0; j < 8; ++j) sv[j] = (short)lsh[dbase + j][col];
    *(short8*)(Bblk + ((size_t)(tile0 + tl) * 4 + kk) * 512 + lane * 8) = sv;
  }
}

// ---------- mega: intra [0,512) | loss1 [512,544) | queue [544,1568) ----------

__global__ __launch_bounds__(256) void mega_k(
    const float* __restrict__ q, const float* __restrict__ kin,
    const unsigned short* __restrict__ Bblk, float* __restrict__ ws) {
  __shared__ float l_e[4][32], l_de[4][32];
  const int b    = (int)blockIdx.x;
  const int tid  = (int)threadIdx.x;
  const int lane = tid & 63;
  const int wave = tid >> 6;
  const int quad = lane >> 4;
  const int m    = lane & 15;

  if (b >= MB_L1) {
    // ---- queue GEMM: R2-EXACT shape. 32-row blocks, SUB=4, 32 iters/wave.
    const int fb      = b - MB_L1;            // 544 % 8 == 0 keeps swizzle
    const int xcd     = fb & 7;
    const int t       = fb >> 3;
    const int rowBase = (t & 31) * 32;
    const int sub     = t >> 5;               // 0..3

    short8 a[2][4];
    #pragma unroll
    for (int rg = 0; rg < 2; ++rg)
      #pragma unroll
      for (int kk = 0; kk < 4; ++kk)
        a[rg][kk] = cvt8(q + (size_t)(rowBase + rg * 16 + m) * DDIM + kk * 32 + quad * 8);

    float ae[2][4] = {}, ade[2][4] = {};

    int wt = xcd * SLICE + sub * 4 + wave;
    const int wtEnd = (xcd + 1) * SLICE;
    short8 bc[4];
    {
      const unsigned short* bp = Bblk + (size_t)wt * 2048 + lane * 8;
      #pragma unroll
      for (int kk = 0; kk < 4; ++kk) bc[kk] = *(const short8*)(bp + kk * 512);
    }
    while (true) {
      const int wtn = wt + SUB * 4;
      const bool more = wtn < wtEnd;
      short8 bn[4];
      if (more) {
        const unsigned short* bp = Bblk + (size_t)wtn * 2048 + lane * 8;
        #pragma unroll
        for (int kk = 0; kk < 4; ++kk) bn[kk] = *(const short8*)(bp + kk * 512);
      }
      #pragma unroll
      for (int rg = 0; rg < 2; ++rg) {
        float4v C = {0.f, 0.f, 0.f, 0.f};
        #pragma unroll
        for (int kk = 0; kk < 4; ++kk)
          C = __builtin_amdgcn_mfma_f32_16x16x32_bf16(a[rg][kk], bc[kk], C, 0, 0, 0);
        #pragma unroll
        for (int r = 0; r < 4; ++r) {
          float d = C[r];
          float e = EXP2(fmaf(d, TWO_LOG2E, -TWO_LOG2E));
          ae[rg][r] += e;
          ade[rg][r] = fmaf(d, e, ade[rg][r]);
        }
      }
      if (!more) break;
      wt = wtn;
      #pragma unroll
      for (int kk = 0; kk < 4; ++kk) bc[kk] = bn[kk];
    }

    #pragma unroll
    for (int rg = 0; rg < 2; ++rg)
      #pragma unroll
      for (int r = 0; r < 4; ++r) {
        float e = ae[rg][r], de = ade[rg][r];
        #pragma unroll
        for (int mk = 8; mk >= 1; mk >>= 1) {
          e  += __shfl_xor(e,  mk, 64);
          de += __shfl_xor(de, mk, 64);
        }
        if (m == 0) {
          l_e[wave][rg * 16 + quad * 4 + r]  = e;
          l_de[wave][rg * 16 + quad * 4 + r] = de;
        }
      }
    __syncthreads();
    if (tid < 32) {
      float E = l_e[0][tid] + l_e[1][tid] + l_e[2][tid] + l_e[3][tid];
      float D = l_de[0][tid] + l_de[1][tid] + l_de[2][tid] + l_de[3][tid];
      const int row = rowBase + tid;
      atomicAdd(&ws[row],        E);
      atomicAdd(&ws[1024 + row], 2.f * (E - D));
    }
  } else if (b < MB_INTRA) {
    // ---- intra 2-rg (verified): b = rowblk | yg<<5 | x<<8
    const int rowblk = b & 31;
    const int yg = (b >> 5) & 7;
    const int x  = b >> 8;
    const float* qx = q + (size_t)x * NROWS * DDIM;
    const int rowBase = rowblk * 32;

    short8 a[2][4];
    #pragma unroll
    for (int rg = 0; rg < 2; ++rg)
      #pragma unroll
      for (int kk = 0; kk < 4; ++kk)
        a[rg][kk] = cvt8(qx + (size_t)(rowBase + rg * 16 + m) * DDIM + kk * 32 + quad * 8);

    float ae[2][4] = {}, ade[2][4] = {};
    for (int jt = yg * 4 + wave; jt < NROWS / 16; jt += 32) {
      short8 bfr[4];
      #pragma unroll
      for (int kk = 0; kk < 4; ++kk)
        bfr[kk] = cvt8(qx + (size_t)(jt * 16 + m) * DDIM + kk * 32 + quad * 8);
      const int dgRg = (jt * 16 - rowBase) >> 4;
      #pragma unroll
      for (int rg = 0; rg < 2; ++rg) {
        float4v C = {0.f, 0.f, 0.f, 0.f};
        #pragma unroll
        for (int kk = 0; kk < 4; ++kk)
          C = __builtin_amdgcn_mfma_f32_16x16x32_bf16(a[rg][kk], bfr[kk], C, 0, 0, 0);
        #pragma unroll
        for (int r = 0; r < 4; ++r) {
          float d = C[r];
          float e = EXP2(fmaf(d, TWO_LOG2E, -TWO_LOG2E));
          float de = d * e;
          if (rg == dgRg && (quad * 4 + r) == m) { e = 0.f; de = 0.f; }
          ae[rg][r] += e;
          ade[rg][r] += de;
        }
      }
    }
    #pragma unroll
    for (int rg = 0; rg < 2; ++rg)
      #pragma unroll
      for (int r = 0; r < 4; ++r) {
        float e = ae[rg][r], de = ade[rg][r];
        #pragma unroll
        for (int mk = 8; mk >= 1; mk >>= 1) {
          e  += __shfl_xor(e,  mk, 64);
          de += __shfl_xor(de, mk, 64);
        }
        if (m == 0) {
          l_e[wave][rg * 16 + quad * 4 + r]  = e;
          l_de[wave][rg * 16 + quad * 4 + r] = de;
        }
      }
    __syncthreads();
    if (tid < 32) {
      float E = l_e[0][tid] + l_e[1][tid] + l_e[2][tid] + l_e[3][tid];
      float D = l_de[0][tid] + l_de[1][tid] + l_de[2][tid] + l_de[3][tid];
      const int slot = x * 8 + yg;
      ws[IPART + (size_t)slot * 2048 + rowBase + tid]        = E;
      ws[IPART + (size_t)slot * 2048 + 1024 + rowBase + tid] = D;
    }
  } else {
    // ---- loss1 (verified): wave handles 16 (x,i) rows
    const int gw0 = (b - MB_INTRA) * 4 + wave;   // 0..127
    for (int t = 0; t < 16; ++t) {
      const int idx = gw0 * 16 + t;              // 0..2047
      const int x = idx >> 10;
      const int i = idx & 1023;
      const float2* qp = (const float2*)(q + (size_t)(x * NROWS + i) * DDIM);
      const float2* kp = (const float2*)(kin + (size_t)((1 - x) * NROWS + i) * DDIM);
      float2 av = qp[lane];
      float2 bv = kp[lane];
      float s = wave_sum(av.x * bv.x + av.y * bv.y);
      if (lane == 0) ws[6144 + idx] = s;
    }
  }
}

// ---------- final3: IPart reduce + loss2 + loss1 fold, 1024 threads ----------

__global__ __launch_bounds__(1024) void final3_k(const float* __restrict__ ws,
                                                 float* __restrict__ out) {
  const float* l1part = ws + 6144;
  __shared__ float red1[1024], red2[1024];
  const int tid = (int)threadIdx.x;
  float p1 = 0.f, p2 = 0.f;
  for (int idx = tid; idx < 2048; idx += 1024) {
    int x = idx >> 10;
    int i = idx & 1023;
    p1 += 2.f - 2.f * l1part[idx];
    float E = 0.f, D = 0.f;
    #pragma unroll
    for (int g = 0; g < 8; ++g) {
      const int s = x * 8 + g;
      E += ws[IPART + (size_t)s * 2048 + i];
      D += ws[IPART + (size_t)s * 2048 + 1024 + i];
    }
    float den = ws[i]        + E;
    float num = ws[1024 + i] + 2.f * (E - D);
    p2 += num / den;
  }
  red1[tid] = p1;
  red2[tid] = p2;
  __syncthreads();
  for (int s = 512; s > 0; s >>= 1) {
    if (tid < s) {
      red1[tid] += red1[tid + s];
      red2[tid] += red2[tid + s];
    }
    __syncthreads();
  }
  if (tid == 0) {
    out[0] = red1[0] * (1.f / (2.f * NROWS));
    out[1] = -red2[0] * (1.f / (2.f * NROWS));
  }
}

// ---------- chunked fallback (ws too small for full Bblk) ----------

__global__ void conv_B_ck(const float* __restrict__ queue,
                          unsigned short* __restrict__ Bblk, int c0chunk) {
  const int tid  = (int)threadIdx.x;
  const int g    = tid >> 4;
  const int ci   = (tid & 15) * 4;
  const int cloc = (int)blockIdx.x * 64 + ci;
  const int c    = c0chunk + cloc;
  const int d0   = g * 8;
  const int kk   = g >> 2;
  const int quad = g & 3;
  float4v v[8];
  #pragma unroll
  for (int dd = 0; dd < 8; ++dd)
    v[dd] = *(const float4v*)(queue + (size_t)(d0 + dd) * KQ + c);
  unsigned short* outp = Bblk + ((size_t)(cloc >> 4) * 4 + kk) * 512
                              + (quad * 16 + (cloc & 15)) * 8;
  #pragma unroll
  for (int n = 0; n < 4; ++n) {
    short8 s;
    #pragma unroll
    for (int dd = 0; dd < 8; ++dd)
      s[dd] = (short)f2bf(v[dd][n]);
    *(short8*)(outp + n * 8) = s;
  }
}

__global__ __launch_bounds__(256) void mfma_queue_ck(
    const float* __restrict__ q, const unsigned short* __restrict__ Bblk,
    int cnt, float* __restrict__ acc_e, float* __restrict__ acc_ce) {
  const int lane = (int)threadIdx.x & 63;
  const int wave = (int)threadIdx.x >> 6;
  const int quad = lane >> 4;
  const int m    = lane & 15;
  const int rowBase = (int)blockIdx.x * 64;

  short8 a[4][4];
  #pragma unroll
  for (int rg = 0; rg < 4; ++rg)
    #pragma unroll
    for (int kk = 0; kk < 4; ++kk)
      a[rg][kk] = cvt8(q + (size_t)(rowBase + rg * 16 + m) * DDIM + kk * 32 + quad * 8);

  float ae[4][4] = {}, ade[4][4] = {};
  const int stride = (int)gridDim.y * 4;
  int wt = (int)blockIdx.y * 4 + wave;
  if (wt < cnt) {
    short8 bc[4];
    {
      const unsigned short* bp = Bblk + (size_t)wt * 2048 + lane * 8;
      #pragma unroll
      for (int kk = 0; kk < 4; ++kk) bc[kk] = *(const short8*)(bp + kk * 512);
    }
    while (true) {
      const int wtn = wt + stride;
      const bool more = wtn < cnt;
      short8 bn[4];
      if (more) {
        const unsigned short* bp = Bblk + (size_t)wtn * 2048 + lane * 8;
        #pragma unroll
        for (int kk = 0; kk < 4; ++kk) bn[kk] = *(const short8*)(bp + kk * 512);
      }
      #pragma unroll
      for (int rg = 0; rg < 4; ++rg) {
        float4v C = {0.f, 0.f, 0.f, 0.f};
        #pragma unroll
        for (int kk = 0; kk < 4; ++kk)
          C = __builtin_amdgcn_mfma_f32_16x16x32_bf16(a[rg][kk], bc[kk], C, 0, 0, 0);
        #pragma unroll
        for (int r = 0; r < 4; ++r) {
          float d = C[r];
          float e = EXP2(fmaf(d, TWO_LOG2E, -TWO_LOG2E));
          ae[rg][r] += e;
          ade[rg][r] = fmaf(d, e, ade[rg][r]);
        }
      }
      if (!more) break;
      wt = wtn;
      #pragma unroll
      for (int kk = 0; kk < 4; ++kk) bc[kk] = bn[kk];
    }
  }
  #pragma unroll
  for (int rg = 0; rg < 4; ++rg)
    #pragma unroll
    for (int r = 0; r < 4; ++r) {
      float e = ae[rg][r], de = ade[rg][r];
      #pragma unroll
      for (int mk = 8; mk >= 1; mk >>= 1) {
        e  += __shfl_xor(e,  mk, 64);
        de += __shfl_xor(de, mk, 64);
      }
      if (m == 0) {
        int row = rowBase + rg * 16 + quad * 4 + r;
        atomicAdd(&acc_e[row],  e);
        atomicAdd(&acc_ce[row], 2.f * (e - de));
      }
    }
}

// fallback intra (4-rg)
__global__ __launch_bounds__(256) void mfma_intra(
    const float* __restrict__ q, float* __restrict__ ws) {
  const int x  = (int)blockIdx.z;
  const int yg = (int)blockIdx.y;
  const float* qx = q + (size_t)x * NROWS * DDIM;
  const int lane = (int)threadIdx.x & 63;
  const int wave = (int)threadIdx.x >> 6;
  const int quad = lane >> 4;
  const int m    = lane & 15;
  const int rowBase = (int)blockIdx.x * 64;

  __shared__ float l_e[4][64], l_de[4][64];

  short8 a[4][4];
  #pragma unroll
  for (int rg = 0; rg < 4; ++rg)
    #pragma unroll
    for (int kk = 0; kk < 4; ++kk)
      a[rg][kk] = cvt8(qx + (size_t)(rowBase + rg * 16 + m) * DDIM + kk * 32 + quad * 8);

  float ae[4][4] = {}, ade[4][4] = {};
  for (int jt = yg * 4 + wave; jt < NROWS / 16; jt += 32) {
    short8 bfr[4];
    #pragma unroll
    for (int kk = 0; kk < 4; ++kk)
      bfr[kk] = cvt8(qx + (size_t)(jt * 16 + m) * DDIM + kk * 32 + quad * 8);
    const int dgRg = (jt * 16 - rowBase) >> 4;
    #pragma unroll
    for (int rg = 0; rg < 4; ++rg) {
      float4v C = {0.f, 0.f, 0.f, 0.f};
      #pragma unroll
      for (int kk = 0; kk < 4; ++kk)
        C = __builtin_amdgcn_mfma_f32_16x16x32_bf16(a[rg][kk], bfr[kk], C, 0, 0, 0);
      #pragma unroll
      for (int r = 0; r < 4; ++r) {
        float d = C[r];
        float e = EXP2(fmaf(d, TWO_LOG2E, -TWO_LOG2E));
        float de = d * e;
        if (rg == dgRg && (quad * 4 + r) == m) { e = 0.f; de = 0.f; }
        ae[rg][r] += e;
        ade[rg][r] += de;
      }
    }
  }
  #pragma unroll
  for (int rg = 0; rg < 4; ++rg)
    #pragma unroll
    for (int r = 0; r < 4; ++r) {
      float e = ae[rg][r], de = ade[rg][r];
      #pragma unroll
      for (int mk = 8; mk >= 1; mk >>= 1) {
        e  += __shfl_xor(e,  mk, 64);
        de += __shfl_xor(de, mk, 64);
      }
      if (m == 0) {
        l_e[wave][rg * 16 + quad * 4 + r]  = e;
        l_de[wave][rg * 16 + quad * 4 + r] = de;
      }
    }
  __syncthreads();
  const int tid = (int)threadIdx.x;
  if (tid < 64) {
    float E = l_e[0][tid] + l_e[1][tid] + l_e[2][tid] + l_e[3][tid];
    float D = l_de[0][tid] + l_de[1][tid] + l_de[2][tid] + l_de[3][tid];
    const int slot = x * 8 + yg;
    ws[IPART + (size_t)slot * 2048 + rowBase + tid]        = E;
    ws[IPART + (size_t)slot * 2048 + 1024 + rowBase + tid] = D;
  }
}

__global__ void loss1_k(const float* __restrict__ q, const float* __restrict__ k,
                        float* __restrict__ l1part) {
  int gw   = (int)(blockIdx.x * blockDim.x + threadIdx.x) >> 6;
  int lane = (int)threadIdx.x & 63;
  int x = gw >> 10;
  int i = gw & 1023;
  const float2* qp = (const float2*)(q + (size_t)(x * NROWS + i) * DDIM);
  const float2* kp = (const float2*)(k + (size_t)((1 - x) * NROWS + i) * DDIM);
  float2 a = qp[lane];
  float2 b = kp[lane];
  float s = wave_sum(a.x * b.x + a.y * b.y);
  if (lane == 0) l1part[gw] = s;
}

extern "C" void kernel_launch(void* const* d_in, const int* in_sizes, int n_in,
                              void* d_out, int out_size, void* d_ws, size_t ws_size,
                              hipStream_t stream) {
  const float* q     = (const float*)d_in[0];   // [2][1024][128]
  const float* k     = (const float*)d_in[1];   // [2][1024][128]
  const float* queue = (const float*)d_in[2];   // [128][65536]
  float* ws  = (float*)d_ws;
  float* out = (float*)d_out;
  unsigned short* Bblk = (unsigned short*)((char*)d_ws + BBLK_BYTE_OFF);

  const size_t needFull = BBLK_BYTE_OFF + (size_t)NTILE * 4096;   // 2MB hdr + 16MB
  if (ws_size >= needFull) {
    hipLaunchKernelGGL(conv_k, dim3(512), dim3(256), 0, stream, queue, Bblk, ws);
    hipLaunchKernelGGL(mega_k, dim3(MB_TOTAL), dim3(256), 0, stream,
                       q, k, Bblk, ws);
    hipLaunchKernelGGL(final3_k, dim3(1), dim3(1024), 0, stream, ws, out);
  } else {
    // fallback: chunked queue path with atomics into QS (zeroed first)
    unsigned short* Bsmall = (unsigned short*)((char*)d_ws + 512 * 1024);
    hipLaunchKernelGGL(zero_ws, dim3(8), dim3(256), 0, stream, ws);
    hipLaunchKernelGGL(mfma_intra, dim3(16, 8, 2), dim3(256), 0, stream, q, ws);
    hipLaunchKernelGGL(loss1_k, dim3(512), dim3(256), 0, stream, q, k, ws + 6144);
    size_t avail = (ws_size > 512 * 1024) ? (ws_size - 512 * 1024) : 16384;
    int maxJt = (int)(avail / 4096);
    maxJt &= ~3;
    if (maxJt > NTILE) maxJt = NTILE;
    if (maxJt < 4) maxJt = 4;
    int nch = (NTILE + maxJt - 1) / maxJt;
    for (int c = 0; c < nch; ++c) {
      int jt0  = c * maxJt;
      int cntc = NTILE - jt0; if (cntc > maxJt) cntc = maxJt;
      hipLaunchKernelGGL(conv_B_ck, dim3(cntc / 4), dim3(256), 0, stream,
                         queue, Bsmall, jt0 * 16);
      int gy = (cntc + 3) / 4; if (gy > 64) gy = 64;
      hipLaunchKernelGGL(mfma_queue_ck, dim3(16, gy), dim3(256), 0, stream,
                         q, Bsmall, cntc, ws, ws + 1024);
    }
    hipLaunchKernelGGL(final3_k, dim3(1), dim3(1024), 0, stream, ws, out);
  }
}